// Round 1
// baseline (261.935 us; speedup 1.0000x reference)
//
#include <hip/hip_runtime.h>
#include <cstdint>

// EdgeConv on MI355X.
// Decomposition: msg_e = A[dst] + B[src], A = x@(W1-W2)+b, B = x@W2.
// agg[i] = A[i] + max_{e: dst=i} B[src_e]  (A constant per segment).
// out = relu(agg), 0 for isolated nodes.

#define C_CH 128
#define TWO_C 256

static inline size_t align_up(size_t v, size_t a) { return (v + a - 1) & ~(a - 1); }

// ---- kernel 0: combined weight Wc[128][256]: cols 0..127 = W1-W2, 128..255 = W2 ----
__global__ void build_wc(const float* __restrict__ W, float* __restrict__ Wc) {
    int idx = blockIdx.x * 256 + threadIdx.x;
    if (idx >= 128 * 256) return;
    int k = idx >> 8, j = idx & 255;
    float v;
    if (j < 128) v = W[k * 128 + j] - W[(k + 128) * 128 + j];
    else         v = W[(k + 128) * 128 + (j - 128)];
    Wc[idx] = v;
}

// ---- kernel 1: AB[N][256] = x[N][128] @ Wc[128][256]; +bias on cols<128 ----
__global__ __launch_bounds__(256) void gemm_ab(const float* __restrict__ x,
                                               const float* __restrict__ Wc,
                                               const float* __restrict__ bias,
                                               float* __restrict__ AB, int Nn) {
    __shared__ float xs[64][65];
    __shared__ float ws[64][65];
    int tid = threadIdx.x;
    int tx = tid & 15, ty = tid >> 4;
    int row0 = blockIdx.x * 64, col0 = blockIdx.y * 64;
    float acc[4][4] = {};
    for (int kt = 0; kt < 128; kt += 64) {
        for (int idx = tid; idx < 64 * 64; idx += 256) {
            int r = idx >> 6, k = idx & 63;
            int gr = row0 + r;
            xs[r][k] = (gr < Nn) ? x[gr * C_CH + kt + k] : 0.f;
        }
        for (int idx = tid; idx < 64 * 64; idx += 256) {
            int k = idx >> 6, cc = idx & 63;
            ws[k][cc] = Wc[(kt + k) * TWO_C + col0 + cc];
        }
        __syncthreads();
#pragma unroll
        for (int k = 0; k < 64; ++k) {
            float a[4], bb[4];
#pragma unroll
            for (int i = 0; i < 4; ++i) a[i] = xs[ty + 16 * i][k];
#pragma unroll
            for (int j = 0; j < 4; ++j) bb[j] = ws[k][tx + 16 * j];
#pragma unroll
            for (int i = 0; i < 4; ++i)
#pragma unroll
                for (int j = 0; j < 4; ++j) acc[i][j] += a[i] * bb[j];
        }
        __syncthreads();
    }
#pragma unroll
    for (int i = 0; i < 4; ++i) {
        int gr = row0 + ty + 16 * i;
        if (gr >= Nn) continue;
#pragma unroll
        for (int j = 0; j < 4; ++j) {
            int gc = col0 + tx + 16 * j;
            float v = acc[i][j];
            if (gc < C_CH) v += bias[gc];
            AB[gr * TWO_C + gc] = v;
        }
    }
}

// ---- kernel 2: degree histogram over dst ----
__global__ void hist_k(const int* __restrict__ dst, int* __restrict__ deg, int E_) {
    int i = blockIdx.x * blockDim.x + threadIdx.x;
    if (i < E_) atomicAdd(&deg[dst[i]], 1);
}

// ---- kernel 3: exclusive prefix sum (single block, chunked Hillis-Steele) ----
__global__ __launch_bounds__(1024) void scan_k(const int* __restrict__ deg,
                                               int* __restrict__ offs,
                                               int* __restrict__ cursor, int n) {
    __shared__ int buf[1024];
    int tid = threadIdx.x;
    int running = 0;
    for (int base = 0; base < n; base += 1024) {
        int v = (base + tid < n) ? deg[base + tid] : 0;
        buf[tid] = v;
        __syncthreads();
        int val = v;
        for (int off = 1; off < 1024; off <<= 1) {
            int t = (tid >= off) ? buf[tid - off] : 0;
            __syncthreads();
            val += t;
            buf[tid] = val;
            __syncthreads();
        }
        int excl = val - v;
        if (base + tid < n) {
            offs[base + tid] = running + excl;
            cursor[base + tid] = running + excl;
        }
        int total = buf[1023];
        __syncthreads();  // protect buf[1023] before next chunk's overwrite
        running += total;
    }
    if (tid == 0) offs[n] = running;
}

// ---- kernel 4: scatter src into CSR order ----
__global__ void scatter_k(const int* __restrict__ src, const int* __restrict__ dst,
                          int* __restrict__ cursor, int* __restrict__ ssrc, int E_) {
    int i = blockIdx.x * blockDim.x + threadIdx.x;
    if (i < E_) {
        int d = dst[i];
        int pos = atomicAdd(&cursor[d], 1);
        ssrc[pos] = src[i];
    }
}

// ---- kernel 5: per-node segmented max of B rows + epilogue ----
__global__ __launch_bounds__(128) void node_max(const float* __restrict__ AB,
                                                const int* __restrict__ offs,
                                                const int* __restrict__ ssrc,
                                                float* __restrict__ out, int Nn) {
    int i = blockIdx.x;
    int c = threadIdx.x;  // channel 0..127
    int s = offs[i], e = offs[i + 1];
    __shared__ int js[128];
    float m = -INFINITY;
    for (int base = s; base < e; base += 128) {
        int k = base + c;
        js[c] = (k < e) ? ssrc[k] : 0;
        __syncthreads();
        int cnt = min(128, e - base);
#pragma unroll 4
        for (int t = 0; t < cnt; ++t) {
            int j = js[t];
            m = fmaxf(m, AB[j * TWO_C + C_CH + c]);
        }
        __syncthreads();
    }
    float a = AB[i * TWO_C + c];
    float r = (e > s) ? fmaxf(a + m, 0.f) : 0.f;
    out[i * C_CH + c] = r;
}

extern "C" void kernel_launch(void* const* d_in, const int* in_sizes, int n_in,
                              void* d_out, int out_size, void* d_ws, size_t ws_size,
                              hipStream_t stream) {
    const float* x = (const float*)d_in[0];   // [N,128]
    const float* W = (const float*)d_in[1];   // [256,128]
    const float* b = (const float*)d_in[2];   // [128]
    const int* src = (const int*)d_in[3];     // [E]
    const int* dst = (const int*)d_in[4];     // [E]
    float* out = (float*)d_out;

    const int N = in_sizes[0] / C_CH;
    const int E = in_sizes[3];

    // workspace layout
    char* w = (char*)d_ws;
    float* AB = (float*)w;      w += align_up((size_t)N * TWO_C * 4, 256);
    float* Wc = (float*)w;      w += align_up((size_t)128 * TWO_C * 4, 256);
    int* deg = (int*)w;         w += align_up((size_t)N * 4, 256);
    int* offs = (int*)w;        w += align_up((size_t)(N + 1) * 4, 256);
    int* cursor = (int*)w;      w += align_up((size_t)N * 4, 256);
    int* ssrc = (int*)w;        w += align_up((size_t)E * 4, 256);

    hipMemsetAsync(deg, 0, (size_t)N * 4, stream);

    build_wc<<<(128 * 256 + 255) / 256, 256, 0, stream>>>(W, Wc);

    dim3 ggrid((N + 63) / 64, TWO_C / 64);
    gemm_ab<<<ggrid, 256, 0, stream>>>(x, Wc, b, AB, N);

    hist_k<<<(E + 255) / 256, 256, 0, stream>>>(dst, deg, E);
    scan_k<<<1, 1024, 0, stream>>>(deg, offs, cursor, N);
    scatter_k<<<(E + 255) / 256, 256, 0, stream>>>(src, dst, cursor, ssrc, E);

    node_max<<<N, 128, 0, stream>>>(AB, offs, ssrc, out, N);
}

// Round 2
// 199.048 us; speedup vs baseline: 1.3159x; 1.3159x over previous
//
#include <hip/hip_runtime.h>
#include <cstdint>

// EdgeConv on MI355X.
// msg_e = A[dst] + B[src], A = x@(W1-W2)+b, B = x@W2.
// agg[i] = A[i] + max_{e: dst=i} B[src_e]  (A constant per segment).
// out = relu(agg), 0 for isolated nodes.

#define C_CH 128
#define TWO_C 256

static inline size_t align_up(size_t v, size_t a) { return (v + a - 1) & ~(a - 1); }

// ---- kernel 1: AB[N][256] = x[N][128] @ Wc[128][256]; Wc built inline from W.
// cols 0..127 of Wc = W1-W2 (+bias in epilogue), cols 128..255 = W2.
__global__ __launch_bounds__(256) void gemm_ab(const float* __restrict__ x,
                                               const float* __restrict__ W,
                                               const float* __restrict__ bias,
                                               float* __restrict__ AB, int Nn) {
    __shared__ float xs[64][68];   // 68: keep rows 16B-aligned for float4 reads
    __shared__ float ws[64][64];
    int tid = threadIdx.x;
    int tx = tid & 15;   // 4 consecutive output cols: tx*4..tx*4+3
    int ty = tid >> 4;   // 4 consecutive output rows: ty*4..ty*4+3
    int row0 = blockIdx.x * 64, col0 = blockIdx.y * 64;
    float acc[4][4] = {};
    for (int kt = 0; kt < 128; kt += 64) {
        for (int idx = tid; idx < 64 * 64; idx += 256) {
            int r = idx >> 6, k = idx & 63;
            int gr = row0 + r;
            xs[r][k] = (gr < Nn) ? x[gr * C_CH + kt + k] : 0.f;
        }
        if (col0 < C_CH) {  // block-uniform branch
            for (int idx = tid; idx < 64 * 64; idx += 256) {
                int k = idx >> 6, cc = idx & 63;
                int gk = kt + k, gc = col0 + cc;
                ws[k][cc] = W[gk * C_CH + gc] - W[(gk + C_CH) * C_CH + gc];
            }
        } else {
            for (int idx = tid; idx < 64 * 64; idx += 256) {
                int k = idx >> 6, cc = idx & 63;
                int gk = kt + k, gc = col0 + cc - C_CH;
                ws[k][cc] = W[(gk + C_CH) * C_CH + gc];
            }
        }
        __syncthreads();
#pragma unroll
        for (int k4 = 0; k4 < 16; ++k4) {
            float4 a4[4], b4[4];
#pragma unroll
            for (int i = 0; i < 4; ++i) a4[i] = *(const float4*)&xs[ty * 4 + i][k4 * 4];
#pragma unroll
            for (int kk = 0; kk < 4; ++kk) b4[kk] = *(const float4*)&ws[k4 * 4 + kk][tx * 4];
#pragma unroll
            for (int i = 0; i < 4; ++i) {
                const float* ap = (const float*)&a4[i];
#pragma unroll
                for (int kk = 0; kk < 4; ++kk) {
                    float av = ap[kk];
                    acc[i][0] += av * b4[kk].x;
                    acc[i][1] += av * b4[kk].y;
                    acc[i][2] += av * b4[kk].z;
                    acc[i][3] += av * b4[kk].w;
                }
            }
        }
        __syncthreads();
    }
    int gc0 = col0 + tx * 4;
    float4 badd = make_float4(0.f, 0.f, 0.f, 0.f);
    if (gc0 < C_CH) badd = *(const float4*)&bias[gc0];
#pragma unroll
    for (int i = 0; i < 4; ++i) {
        int gr = row0 + ty * 4 + i;
        if (gr >= Nn) continue;
        float4 v = make_float4(acc[i][0] + badd.x, acc[i][1] + badd.y,
                               acc[i][2] + badd.z, acc[i][3] + badd.w);
        *(float4*)&AB[(size_t)gr * TWO_C + gc0] = v;
    }
}

// ---- kernel 2: degree histogram + per-edge rank (coalesced rank write) ----
__global__ void hist_k(const int* __restrict__ dst, int* __restrict__ deg,
                       int* __restrict__ rank, int E_) {
    int i = blockIdx.x * blockDim.x + threadIdx.x;
    if (i < E_) rank[i] = atomicAdd(&deg[dst[i]], 1);
}

// ---- kernel 3: exclusive prefix sum, single block, wave-shuffle scan ----
// requires n <= 16384 (N = 10000 here)
__global__ __launch_bounds__(1024) void scan_k(const int* __restrict__ deg,
                                               int* __restrict__ offs, int n) {
    __shared__ int wsum[16];
    const int PER = 16;
    int tid = threadIdx.x;
    int base = tid * PER;
    int s = 0;
#pragma unroll
    for (int k = 0; k < PER; ++k) {
        int idx = base + k;
        s += (idx < n) ? deg[idx] : 0;
    }
    int lane = tid & 63, wid = tid >> 6;
    int pref = s;
#pragma unroll
    for (int off = 1; off < 64; off <<= 1) {
        int t = __shfl_up(pref, off);
        if (lane >= off) pref += t;
    }
    if (lane == 63) wsum[wid] = pref;
    __syncthreads();
    if (tid < 16) {
        int v = wsum[tid];
#pragma unroll
        for (int off = 1; off < 16; off <<= 1) {
            int t = __shfl_up(v, off, 16);
            if (tid >= off) v += t;
        }
        wsum[tid] = v;  // inclusive wave sums
    }
    __syncthreads();
    int run = ((wid > 0) ? wsum[wid - 1] : 0) + (pref - s);  // exclusive thread base
#pragma unroll
    for (int k = 0; k < PER; ++k) {
        int idx = base + k;
        int v = (idx < n) ? deg[idx] : 0;
        if (idx < n) offs[idx] = run;
        run += v;
    }
    if (tid == 1023) offs[n] = run;  // total (all this thread's idx >= n)
}

// ---- kernel 4: scatter src into CSR order — NO atomics ----
__global__ void scatter_k(const int* __restrict__ src, const int* __restrict__ dst,
                          const int* __restrict__ offs, const int* __restrict__ rank,
                          int* __restrict__ ssrc, int E_) {
    int i = blockIdx.x * blockDim.x + threadIdx.x;
    if (i < E_) ssrc[offs[dst[i]] + rank[i]] = src[i];
}

// ---- kernel 5: per-node segmented max of B rows + epilogue ----
__global__ __launch_bounds__(128) void node_max(const float* __restrict__ AB,
                                                const int* __restrict__ offs,
                                                const int* __restrict__ ssrc,
                                                float* __restrict__ out, int Nn) {
    int i = blockIdx.x;
    int c = threadIdx.x;  // channel 0..127
    int s = offs[i], e = offs[i + 1];
    __shared__ int js[128];
    float m0 = -INFINITY, m1 = -INFINITY;
    for (int base = s; base < e; base += 128) {
        int k = base + c;
        js[c] = (k < e) ? ssrc[k] : 0;
        __syncthreads();
        int cnt = min(128, e - base);
        int t = 0;
        for (; t + 1 < cnt; t += 2) {
            m0 = fmaxf(m0, AB[(size_t)js[t] * TWO_C + C_CH + c]);
            m1 = fmaxf(m1, AB[(size_t)js[t + 1] * TWO_C + C_CH + c]);
        }
        if (t < cnt) m0 = fmaxf(m0, AB[(size_t)js[t] * TWO_C + C_CH + c]);
        __syncthreads();
    }
    float m = fmaxf(m0, m1);
    float a = AB[(size_t)i * TWO_C + c];
    out[(size_t)i * C_CH + c] = (e > s) ? fmaxf(a + m, 0.f) : 0.f;
}

extern "C" void kernel_launch(void* const* d_in, const int* in_sizes, int n_in,
                              void* d_out, int out_size, void* d_ws, size_t ws_size,
                              hipStream_t stream) {
    const float* x = (const float*)d_in[0];   // [N,128]
    const float* W = (const float*)d_in[1];   // [256,128]
    const float* b = (const float*)d_in[2];   // [128]
    const int* src = (const int*)d_in[3];     // [E]
    const int* dst = (const int*)d_in[4];     // [E]
    float* out = (float*)d_out;

    const int N = in_sizes[0] / C_CH;
    const int E = in_sizes[3];

    // workspace layout
    char* w = (char*)d_ws;
    float* AB = (float*)w;   w += align_up((size_t)N * TWO_C * 4, 256);
    int* deg = (int*)w;      w += align_up((size_t)N * 4, 256);
    int* offs = (int*)w;     w += align_up((size_t)(N + 1) * 4, 256);
    int* rank = (int*)w;     w += align_up((size_t)E * 4, 256);
    int* ssrc = (int*)w;     w += align_up((size_t)E * 4, 256);

    hipMemsetAsync(deg, 0, (size_t)N * 4, stream);

    dim3 ggrid((N + 63) / 64, TWO_C / 64);
    gemm_ab<<<ggrid, 256, 0, stream>>>(x, W, b, AB, N);

    hist_k<<<(E + 255) / 256, 256, 0, stream>>>(dst, deg, rank, E);
    scan_k<<<1, 1024, 0, stream>>>(deg, offs, N);
    scatter_k<<<(E + 255) / 256, 256, 0, stream>>>(src, dst, offs, rank, ssrc, E);

    node_max<<<N, 128, 0, stream>>>(AB, offs, ssrc, out, N);
}

// Round 3
// 174.352 us; speedup vs baseline: 1.5023x; 1.1416x over previous
//
#include <hip/hip_runtime.h>
#include <cstdint>

// EdgeConv on MI355X.
// msg_e = A[dst] + B[src], A = x@(W1-W2)+b, B = x@W2.
// agg[i] = A[i] + max_{e: dst=i} B[src_e]  (A constant per segment).
// out = relu(agg), 0 for isolated nodes.

#define C_CH 128
#define TWO_C 256

static inline size_t align_up(size_t v, size_t a) { return (v + a - 1) & ~(a - 1); }

// ---- kernel 1: AB[N][256] = x @ Wc (Wc built inline) + fused degree/rank histogram.
// cols 0..127 of Wc = W1-W2 (+bias in epilogue), cols 128..255 = W2.
__global__ __launch_bounds__(256) void gemm_hist(const float* __restrict__ x,
                                                 const float* __restrict__ W,
                                                 const float* __restrict__ bias,
                                                 float* __restrict__ AB, int Nn,
                                                 const int* __restrict__ dst,
                                                 int* __restrict__ deg,
                                                 int* __restrict__ rank, int E_) {
    __shared__ float xs[64][68];   // 68: rows 16B-aligned for float4 reads
    __shared__ float ws[64][64];
    int tid = threadIdx.x;
    int tx = tid & 15;   // 4 consecutive output cols
    int ty = tid >> 4;   // 4 consecutive output rows
    int row0 = blockIdx.x * 64, col0 = blockIdx.y * 64;
    float acc[4][4] = {};
    for (int kt = 0; kt < 128; kt += 64) {
        for (int idx = tid; idx < 64 * 64; idx += 256) {
            int r = idx >> 6, k = idx & 63;
            int gr = row0 + r;
            xs[r][k] = (gr < Nn) ? x[gr * C_CH + kt + k] : 0.f;
        }
        if (col0 < C_CH) {  // block-uniform branch
            for (int idx = tid; idx < 64 * 64; idx += 256) {
                int k = idx >> 6, cc = idx & 63;
                int gk = kt + k, gc = col0 + cc;
                ws[k][cc] = W[gk * C_CH + gc] - W[(gk + C_CH) * C_CH + gc];
            }
        } else {
            for (int idx = tid; idx < 64 * 64; idx += 256) {
                int k = idx >> 6, cc = idx & 63;
                int gk = kt + k, gc = col0 + cc - C_CH;
                ws[k][cc] = W[(gk + C_CH) * C_CH + gc];
            }
        }
        __syncthreads();
#pragma unroll
        for (int k4 = 0; k4 < 16; ++k4) {
            float4 a4[4], b4[4];
#pragma unroll
            for (int i = 0; i < 4; ++i) a4[i] = *(const float4*)&xs[ty * 4 + i][k4 * 4];
#pragma unroll
            for (int kk = 0; kk < 4; ++kk) b4[kk] = *(const float4*)&ws[k4 * 4 + kk][tx * 4];
#pragma unroll
            for (int i = 0; i < 4; ++i) {
                const float* ap = (const float*)&a4[i];
#pragma unroll
                for (int kk = 0; kk < 4; ++kk) {
                    float av = ap[kk];
                    acc[i][0] += av * b4[kk].x;
                    acc[i][1] += av * b4[kk].y;
                    acc[i][2] += av * b4[kk].z;
                    acc[i][3] += av * b4[kk].w;
                }
            }
        }
        __syncthreads();
    }
    int gc0 = col0 + tx * 4;
    float4 badd = make_float4(0.f, 0.f, 0.f, 0.f);
    if (gc0 < C_CH) badd = *(const float4*)&bias[gc0];
#pragma unroll
    for (int i = 0; i < 4; ++i) {
        int gr = row0 + ty * 4 + i;
        if (gr >= Nn) continue;
        float4 v = make_float4(acc[i][0] + badd.x, acc[i][1] + badd.y,
                               acc[i][2] + badd.z, acc[i][3] + badd.w);
        *(float4*)&AB[(size_t)gr * TWO_C + gc0] = v;
    }

    // ---- fused histogram tail: rank[e] = slot of edge e within segment dst[e] ----
    int nthreads = gridDim.x * gridDim.y * 256;
    int gtid = (blockIdx.y * gridDim.x + blockIdx.x) * 256 + tid;
    int E4 = E_ >> 2;
    const int4* dst4 = (const int4*)dst;
    int4* rank4 = (int4*)rank;
    for (int i = gtid; i < E4; i += nthreads) {
        int4 d = dst4[i];
        int4 r;
        r.x = atomicAdd(&deg[d.x], 1);
        r.y = atomicAdd(&deg[d.y], 1);
        r.z = atomicAdd(&deg[d.z], 1);
        r.w = atomicAdd(&deg[d.w], 1);
        rank4[i] = r;
    }
    int rem = E_ & 3;
    if (gtid < rem) {
        int i = E4 * 4 + gtid;
        rank[i] = atomicAdd(&deg[dst[i]], 1);
    }
}

// ---- kernel 2: exclusive prefix sum, single block, wave-shuffle scan (n <= 16384) ----
__global__ __launch_bounds__(1024) void scan_k(const int* __restrict__ deg,
                                               int* __restrict__ offs, int n) {
    __shared__ int wsum[16];
    const int PER = 16;
    int tid = threadIdx.x;
    int base = tid * PER;
    int s = 0;
#pragma unroll
    for (int k = 0; k < PER; ++k) {
        int idx = base + k;
        s += (idx < n) ? deg[idx] : 0;
    }
    int lane = tid & 63, wid = tid >> 6;
    int pref = s;
#pragma unroll
    for (int off = 1; off < 64; off <<= 1) {
        int t = __shfl_up(pref, off);
        if (lane >= off) pref += t;
    }
    if (lane == 63) wsum[wid] = pref;
    __syncthreads();
    if (tid < 16) {
        int v = wsum[tid];
#pragma unroll
        for (int off = 1; off < 16; off <<= 1) {
            int t = __shfl_up(v, off, 16);
            if (tid >= off) v += t;
        }
        wsum[tid] = v;  // inclusive wave sums
    }
    __syncthreads();
    int run = ((wid > 0) ? wsum[wid - 1] : 0) + (pref - s);
#pragma unroll
    for (int k = 0; k < PER; ++k) {
        int idx = base + k;
        int v = (idx < n) ? deg[idx] : 0;
        if (idx < n) offs[idx] = run;
        run += v;
    }
    if (tid == 1023) offs[n] = run;
}

// ---- kernel 3: scatter src into CSR order — no atomics, int4-vectorized ----
__global__ __launch_bounds__(256) void scatter_k(const int* __restrict__ src,
                                                 const int* __restrict__ dst,
                                                 const int* __restrict__ offs,
                                                 const int* __restrict__ rank,
                                                 int* __restrict__ ssrc, int E_) {
    int i = blockIdx.x * 256 + threadIdx.x;
    int E4 = E_ >> 2;
    if (i < E4) {
        int4 s4 = ((const int4*)src)[i];
        int4 d4 = ((const int4*)dst)[i];
        int4 r4 = ((const int4*)rank)[i];
        ssrc[offs[d4.x] + r4.x] = s4.x;
        ssrc[offs[d4.y] + r4.y] = s4.y;
        ssrc[offs[d4.z] + r4.z] = s4.z;
        ssrc[offs[d4.w] + r4.w] = s4.w;
    }
    int rem = E_ & 3;
    if (i < rem) {
        int e = E4 * 4 + i;
        ssrc[offs[dst[e]] + rank[e]] = src[e];
    }
}

// ---- kernel 4: per-node segmented max of B rows + epilogue ----
// 256 threads = 8 groups x 32 lanes; each group reads one edge's 512B B-row
// as float4/lane -> 8 edges in flight per unroll step, 8-deep unroll.
__global__ __launch_bounds__(256) void node_max(const float* __restrict__ AB,
                                                const int* __restrict__ offs,
                                                const int* __restrict__ ssrc,
                                                float* __restrict__ out, int Nn) {
    int i = blockIdx.x;
    int tid = threadIdx.x;
    int s = offs[i], e = offs[i + 1];
    if (e == s) {  // isolated node: zeros (block-uniform early exit)
        if (tid < 32) ((float4*)out)[(size_t)i * 32 + tid] = make_float4(0.f, 0.f, 0.f, 0.f);
        return;
    }
    __shared__ int js[256];
    __shared__ float4 pm[4][32];
    int g = tid >> 5;                    // group 0..7
    int cb = C_CH + (tid & 31) * 4;      // B column base for this lane
    float4 m = make_float4(-INFINITY, -INFINITY, -INFINITY, -INFINITY);
    for (int base = s; base < e; base += 256) {
        __syncthreads();
        js[tid] = ssrc[min(base + tid, e - 1)];
        __syncthreads();
        int cnt = min(256, e - base);
        if (cnt > g) {
            int nt = (cnt - g + 7) >> 3;  // edges for this group (stride 8)
            for (int t = 0; t < nt; t += 8) {
                float4 v[8];
#pragma unroll
                for (int u = 0; u < 8; ++u) {
                    int idx = min(g + 8 * (t + u), cnt - 1);  // clamp: redundant, not wrong
                    v[u] = *(const float4*)&AB[(size_t)js[idx] * TWO_C + cb];
                }
#pragma unroll
                for (int u = 0; u < 8; ++u) {
                    m.x = fmaxf(m.x, v[u].x);
                    m.y = fmaxf(m.y, v[u].y);
                    m.z = fmaxf(m.z, v[u].z);
                    m.w = fmaxf(m.w, v[u].w);
                }
            }
        }
    }
    // cross-group reduce: lanes l and l+32 hold the same channels
    m.x = fmaxf(m.x, __shfl_xor(m.x, 32));
    m.y = fmaxf(m.y, __shfl_xor(m.y, 32));
    m.z = fmaxf(m.z, __shfl_xor(m.z, 32));
    m.w = fmaxf(m.w, __shfl_xor(m.w, 32));
    int wid = tid >> 6;
    if ((tid & 63) < 32) pm[wid][tid & 31] = m;
    __syncthreads();
    if (tid < 32) {
        float4 a = ((const float4*)AB)[(size_t)i * 64 + tid];  // A = cols 0..127
        float4 r0 = pm[0][tid], r1 = pm[1][tid], r2 = pm[2][tid], r3 = pm[3][tid];
        float4 mm;
        mm.x = fmaxf(fmaxf(r0.x, r1.x), fmaxf(r2.x, r3.x));
        mm.y = fmaxf(fmaxf(r0.y, r1.y), fmaxf(r2.y, r3.y));
        mm.z = fmaxf(fmaxf(r0.z, r1.z), fmaxf(r2.z, r3.z));
        mm.w = fmaxf(fmaxf(r0.w, r1.w), fmaxf(r2.w, r3.w));
        float4 o;
        o.x = fmaxf(a.x + mm.x, 0.f);
        o.y = fmaxf(a.y + mm.y, 0.f);
        o.z = fmaxf(a.z + mm.z, 0.f);
        o.w = fmaxf(a.w + mm.w, 0.f);
        ((float4*)out)[(size_t)i * 32 + tid] = o;
    }
}

extern "C" void kernel_launch(void* const* d_in, const int* in_sizes, int n_in,
                              void* d_out, int out_size, void* d_ws, size_t ws_size,
                              hipStream_t stream) {
    const float* x = (const float*)d_in[0];   // [N,128]
    const float* W = (const float*)d_in[1];   // [256,128]
    const float* b = (const float*)d_in[2];   // [128]
    const int* src = (const int*)d_in[3];     // [E]
    const int* dst = (const int*)d_in[4];     // [E]
    float* out = (float*)d_out;

    const int N = in_sizes[0] / C_CH;
    const int E = in_sizes[3];

    char* w = (char*)d_ws;
    float* AB = (float*)w;   w += align_up((size_t)N * TWO_C * 4, 256);
    int* deg = (int*)w;      w += align_up((size_t)N * 4, 256);
    int* offs = (int*)w;     w += align_up((size_t)(N + 1) * 4, 256);
    int* rank = (int*)w;     w += align_up((size_t)E * 4, 256);
    int* ssrc = (int*)w;     w += align_up((size_t)E * 4, 256);

    hipMemsetAsync(deg, 0, (size_t)N * 4, stream);

    dim3 ggrid((N + 63) / 64, TWO_C / 64);
    gemm_hist<<<ggrid, 256, 0, stream>>>(x, W, b, AB, N, dst, deg, rank, E);
    scan_k<<<1, 1024, 0, stream>>>(deg, offs, N);
    scatter_k<<<((E >> 2) + 255) / 256, 256, 0, stream>>>(src, dst, offs, rank, ssrc, E);
    node_max<<<N, 256, 0, stream>>>(AB, offs, ssrc, out, N);
}

// Round 4
// 153.547 us; speedup vs baseline: 1.7059x; 1.1355x over previous
//
#include <hip/hip_runtime.h>
#include <cstdint>

// EdgeConv on MI355X.
// msg_e = A[dst] + B[src], A = x@(W1-W2)+b, B = x@W2.
// agg[i] = A[i] + max_{e: dst=i} B[src_e];  out = relu(agg), 0 for isolated nodes.
// GEMM via bf16x3 MFMA (xh@wh + xl@wh + xh@wl, fp32 acc) -> fp32-level accuracy.
// CSR build via per-block LDS histograms (no global atomic-returns).

#define C_CH 128
#define NBLK_H 64
#define NMAX_LDS 10016

typedef __attribute__((ext_vector_type(8))) short bf16x8;
typedef __attribute__((ext_vector_type(4))) float f32x4;

static inline size_t align_up(size_t v, size_t a) { return (v + a - 1) & ~(a - 1); }

__device__ inline unsigned f2bf_bits(float f) {  // RNE float->bf16 bits
    unsigned u = __builtin_bit_cast(unsigned, f);
    return (u + 0x7FFFu + ((u >> 16) & 1u)) >> 16;
}

// ---- K1 split-grid: blocks [0,64): per-block LDS histogram of dst -> T[b][n]
//      blocks [64,192): build Wt (transposed combined weight) as bf16 hi/lo ----
__global__ __launch_bounds__(256) void prep_k(const float* __restrict__ W,
                                              const int* __restrict__ dst,
                                              int* __restrict__ T,
                                              unsigned short* __restrict__ wth,
                                              unsigned short* __restrict__ wtl,
                                              int E_, int Nn, int chunk) {
    __shared__ int ldeg[NMAX_LDS];
    int tid = threadIdx.x;
    int b = blockIdx.x;
    if (b < NBLK_H) {
        for (int i = tid; i < Nn; i += 256) ldeg[i] = 0;
        __syncthreads();
        int e0 = b * chunk, e1 = min(e0 + chunk, E_);
        int n4 = (e1 - e0) >> 2;
        const int4* d4p = (const int4*)(dst + e0);
        for (int i = tid; i < n4; i += 256) {
            int4 d = d4p[i];
            atomicAdd(&ldeg[d.x], 1); atomicAdd(&ldeg[d.y], 1);
            atomicAdd(&ldeg[d.z], 1); atomicAdd(&ldeg[d.w], 1);
        }
        for (int i = e0 + n4 * 4 + tid; i < e1; i += 256) atomicAdd(&ldeg[dst[i]], 1);
        __syncthreads();
        for (int i = tid; i < Nn; i += 256) T[b * Nn + i] = ldeg[i];
    } else {
        int idx = (b - NBLK_H) * 256 + tid;  // covers 256*128 = 32768 exactly
        if (idx < 2 * C_CH * C_CH) {
            int n = idx >> 7, k = idx & 127;
            float wc;
            if (n < C_CH) wc = W[k * C_CH + n] - W[(k + C_CH) * C_CH + n];
            else          wc = W[(k + C_CH) * C_CH + (n - C_CH)];
            unsigned hb = f2bf_bits(wc);
            float hf = __builtin_bit_cast(float, hb << 16);
            unsigned lb = f2bf_bits(wc - hf);
            wth[idx] = (unsigned short)hb;   // layout: [n][k]
            wtl[idx] = (unsigned short)lb;
        }
    }
}

// ---- K2: column-scan of T across blocks -> exclusive per-block base; deg[n] = total ----
__global__ __launch_bounds__(256) void colscan_k(int* __restrict__ T,
                                                 int* __restrict__ deg, int Nn) {
    int n = blockIdx.x * 256 + threadIdx.x;
    if (n >= Nn) return;
    int s = 0;
#pragma unroll 8
    for (int b = 0; b < NBLK_H; ++b) {
        int t = T[b * Nn + n];
        T[b * Nn + n] = s;
        s += t;
    }
    deg[n] = s;
}

// ---- K3: exclusive prefix sum over deg -> offs (single block, wave-shuffle) ----
__global__ __launch_bounds__(1024) void scan_k(const int* __restrict__ deg,
                                               int* __restrict__ offs, int n) {
    __shared__ int wsum[16];
    const int PER = 16;
    int tid = threadIdx.x;
    int base = tid * PER;
    int s = 0;
#pragma unroll
    for (int k = 0; k < PER; ++k) {
        int idx = base + k;
        s += (idx < n) ? deg[idx] : 0;
    }
    int lane = tid & 63, wid = tid >> 6;
    int pref = s;
#pragma unroll
    for (int off = 1; off < 64; off <<= 1) {
        int t = __shfl_up(pref, off);
        if (lane >= off) pref += t;
    }
    if (lane == 63) wsum[wid] = pref;
    __syncthreads();
    if (tid < 16) {
        int v = wsum[tid];
#pragma unroll
        for (int off = 1; off < 16; off <<= 1) {
            int t = __shfl_up(v, off, 16);
            if (tid >= off) v += t;
        }
        wsum[tid] = v;
    }
    __syncthreads();
    int run = ((wid > 0) ? wsum[wid - 1] : 0) + (pref - s);
#pragma unroll
    for (int k = 0; k < PER; ++k) {
        int idx = base + k;
        int v = (idx < n) ? deg[idx] : 0;
        if (idx < n) offs[idx] = run;
        run += v;
    }
    if (tid == 1023) offs[n] = run;
}

// ---- K3b: fold offs into T: T[b][n] += offs[n] ----
__global__ __launch_bounds__(256) void addoffs_k(int* __restrict__ T,
                                                 const int* __restrict__ offs, int Nn) {
    int n = blockIdx.x * 256 + threadIdx.x;
    int b = blockIdx.y;
    if (n < Nn) T[b * Nn + n] += offs[n];
}

// ---- K4: MFMA GEMM: Aarr[N][128] = x@(W1-W2)+b, Barr[N][128] = x@W2 (bf16x3) ----
__global__ __launch_bounds__(256) void gemm_mfma(const float* __restrict__ x,
                                                 const unsigned short* __restrict__ wth,
                                                 const unsigned short* __restrict__ wtl,
                                                 const float* __restrict__ bias,
                                                 float* __restrict__ Aarr,
                                                 float* __restrict__ Barr, int Nn) {
    __shared__ unsigned short Wh[64][136];  // [col][k], pad 136 -> 2-way bank only
    __shared__ unsigned short Wl[64][136];
    int tid = threadIdx.x;
    int bx = blockIdx.x, by = blockIdx.y;
    int col0 = by * 64;
    for (int idx = tid; idx < 64 * 16; idx += 256) {
        int c = idx >> 4, ch = idx & 15;
        *(bf16x8*)&Wh[c][ch * 8] = *(const bf16x8*)&wth[(col0 + c) * C_CH + ch * 8];
        *(bf16x8*)&Wl[c][ch * 8] = *(const bf16x8*)&wtl[(col0 + c) * C_CH + ch * 8];
    }
    __syncthreads();
    int lane = tid & 63, wv = tid >> 6;
    int r0 = bx * 64 + wv * 16;
    int arow = min(r0 + (lane & 15), Nn - 1);  // clamp: garbage rows guarded at store
    int kgrp = (lane >> 4) * 8;
    f32x4 acc[4] = {};
#pragma unroll
    for (int kk = 0; kk < 4; ++kk) {
        int k0 = kk * 32 + kgrp;
        const float* xp = &x[(size_t)arow * C_CH + k0];
        float4 v0 = *(const float4*)xp;
        float4 v1 = *(const float4*)(xp + 4);
        float vv[8] = {v0.x, v0.y, v0.z, v0.w, v1.x, v1.y, v1.z, v1.w};
        bf16x8 ah, al;
#pragma unroll
        for (int u = 0; u < 8; ++u) {
            unsigned hb = f2bf_bits(vv[u]);
            float hf = __builtin_bit_cast(float, hb << 16);
            ah[u] = (short)hb;
            al[u] = (short)f2bf_bits(vv[u] - hf);
        }
#pragma unroll
        for (int j = 0; j < 4; ++j) {
            int c = j * 16 + (lane & 15);
            bf16x8 bh = *(const bf16x8*)&Wh[c][k0];
            bf16x8 bl = *(const bf16x8*)&Wl[c][k0];
            acc[j] = __builtin_amdgcn_mfma_f32_16x16x32_bf16(ah, bh, acc[j], 0, 0, 0);
            acc[j] = __builtin_amdgcn_mfma_f32_16x16x32_bf16(al, bh, acc[j], 0, 0, 0);
            acc[j] = __builtin_amdgcn_mfma_f32_16x16x32_bf16(ah, bl, acc[j], 0, 0, 0);
        }
    }
    bool isA = (col0 < C_CH);  // block-uniform
#pragma unroll
    for (int j = 0; j < 4; ++j) {
        int gc = col0 + j * 16 + (lane & 15);
        float badd = isA ? bias[gc] : 0.f;
        float* dp = isA ? Aarr : Barr;
        int cc = isA ? gc : gc - C_CH;
#pragma unroll
        for (int reg = 0; reg < 4; ++reg) {
            int row = r0 + (lane >> 4) * 4 + reg;  // C/D layout: col=lane&15, row=(lane>>4)*4+reg
            if (row < Nn) dp[(size_t)row * C_CH + cc] = acc[j][reg] + badd;
        }
    }
}

// ---- K5: scatter into CSR order; ranks re-derived via LDS atomics ----
__global__ __launch_bounds__(256) void scatter2_k(const int* __restrict__ src,
                                                  const int* __restrict__ dst,
                                                  const int* __restrict__ T,
                                                  int* __restrict__ ssrc,
                                                  int E_, int Nn, int chunk) {
    __shared__ int ldeg[NMAX_LDS];
    int tid = threadIdx.x, b = blockIdx.x;
    for (int i = tid; i < Nn; i += 256) ldeg[i] = 0;
    __syncthreads();
    const int* Trow = T + b * Nn;  // = offs[n] + base of this block's group-slice
    int e0 = b * chunk, e1 = min(e0 + chunk, E_);
    int n4 = (e1 - e0) >> 2;
    const int4* d4p = (const int4*)(dst + e0);
    const int4* s4p = (const int4*)(src + e0);
    for (int i = tid; i < n4; i += 256) {
        int4 d = d4p[i];
        int4 s = s4p[i];
        int r0 = atomicAdd(&ldeg[d.x], 1); ssrc[Trow[d.x] + r0] = s.x;
        int r1 = atomicAdd(&ldeg[d.y], 1); ssrc[Trow[d.y] + r1] = s.y;
        int r2 = atomicAdd(&ldeg[d.z], 1); ssrc[Trow[d.z] + r2] = s.z;
        int r3 = atomicAdd(&ldeg[d.w], 1); ssrc[Trow[d.w] + r3] = s.w;
    }
    for (int i = e0 + n4 * 4 + tid; i < e1; i += 256) {
        int d = dst[i];
        int r = atomicAdd(&ldeg[d], 1);
        ssrc[Trow[d] + r] = src[i];
    }
}

// ---- K6: per-node segmented max over Barr rows + epilogue ----
__global__ __launch_bounds__(256) void node_max(const float* __restrict__ Aarr,
                                                const float* __restrict__ Barr,
                                                const int* __restrict__ offs,
                                                const int* __restrict__ ssrc,
                                                float* __restrict__ out, int Nn) {
    int i = blockIdx.x;
    int tid = threadIdx.x;
    int s = offs[i], e = offs[i + 1];
    if (e == s) {
        if (tid < 32) ((float4*)out)[(size_t)i * 32 + tid] = make_float4(0.f, 0.f, 0.f, 0.f);
        return;
    }
    __shared__ int js[256];
    __shared__ float4 pm[4][32];
    int g = tid >> 5;                 // group 0..7, one edge-row per group
    int cb = (tid & 31) * 4;          // channel base
    float4 m = make_float4(-INFINITY, -INFINITY, -INFINITY, -INFINITY);
    for (int base = s; base < e; base += 256) {
        __syncthreads();
        js[tid] = ssrc[min(base + tid, e - 1)];
        __syncthreads();
        int cnt = min(256, e - base);
        if (cnt > g) {
            int nt = (cnt - g + 7) >> 3;
            for (int t = 0; t < nt; t += 8) {
                float4 v[8];
#pragma unroll
                for (int u = 0; u < 8; ++u) {
                    int idx = min(g + 8 * (t + u), cnt - 1);
                    v[u] = *(const float4*)&Barr[(size_t)js[idx] * C_CH + cb];
                }
#pragma unroll
                for (int u = 0; u < 8; ++u) {
                    m.x = fmaxf(m.x, v[u].x);
                    m.y = fmaxf(m.y, v[u].y);
                    m.z = fmaxf(m.z, v[u].z);
                    m.w = fmaxf(m.w, v[u].w);
                }
            }
        }
    }
    m.x = fmaxf(m.x, __shfl_xor(m.x, 32));
    m.y = fmaxf(m.y, __shfl_xor(m.y, 32));
    m.z = fmaxf(m.z, __shfl_xor(m.z, 32));
    m.w = fmaxf(m.w, __shfl_xor(m.w, 32));
    int wid = tid >> 6;
    if ((tid & 63) < 32) pm[wid][tid & 31] = m;
    __syncthreads();
    if (tid < 32) {
        float4 a = ((const float4*)Aarr)[(size_t)i * 32 + tid];
        float4 r0 = pm[0][tid], r1 = pm[1][tid], r2 = pm[2][tid], r3 = pm[3][tid];
        float4 mm;
        mm.x = fmaxf(fmaxf(r0.x, r1.x), fmaxf(r2.x, r3.x));
        mm.y = fmaxf(fmaxf(r0.y, r1.y), fmaxf(r2.y, r3.y));
        mm.z = fmaxf(fmaxf(r0.z, r1.z), fmaxf(r2.z, r3.z));
        mm.w = fmaxf(fmaxf(r0.w, r1.w), fmaxf(r2.w, r3.w));
        float4 o;
        o.x = fmaxf(a.x + mm.x, 0.f);
        o.y = fmaxf(a.y + mm.y, 0.f);
        o.z = fmaxf(a.z + mm.z, 0.f);
        o.w = fmaxf(a.w + mm.w, 0.f);
        ((float4*)out)[(size_t)i * 32 + tid] = o;
    }
}

extern "C" void kernel_launch(void* const* d_in, const int* in_sizes, int n_in,
                              void* d_out, int out_size, void* d_ws, size_t ws_size,
                              hipStream_t stream) {
    const float* x = (const float*)d_in[0];   // [N,128]
    const float* W = (const float*)d_in[1];   // [256,128]
    const float* b = (const float*)d_in[2];   // [128]
    const int* src = (const int*)d_in[3];     // [E]
    const int* dst = (const int*)d_in[4];     // [E]
    float* out = (float*)d_out;

    const int N = in_sizes[0] / C_CH;
    const int E = in_sizes[3];
    const int chunk = (((E + NBLK_H - 1) / NBLK_H) + 3) & ~3;

    char* w = (char*)d_ws;
    float* Aarr = (float*)w;          w += align_up((size_t)N * C_CH * 4, 256);
    float* Barr = (float*)w;          w += align_up((size_t)N * C_CH * 4, 256);
    unsigned short* wth = (unsigned short*)w;  w += align_up((size_t)2 * C_CH * C_CH * 2, 256);
    unsigned short* wtl = (unsigned short*)w;  w += align_up((size_t)2 * C_CH * C_CH * 2, 256);
    int* deg = (int*)w;               w += align_up((size_t)N * 4, 256);
    int* offs = (int*)w;              w += align_up((size_t)(N + 1) * 4, 256);
    int* T = (int*)w;                 w += align_up((size_t)NBLK_H * N * 4, 256);
    int* ssrc = (int*)w;              w += align_up((size_t)E * 4, 256);

    prep_k<<<NBLK_H + 128, 256, 0, stream>>>(W, dst, T, wth, wtl, E, N, chunk);
    colscan_k<<<(N + 255) / 256, 256, 0, stream>>>(T, deg, N);
    scan_k<<<1, 1024, 0, stream>>>(deg, offs, N);
    addoffs_k<<<dim3((N + 255) / 256, NBLK_H), 256, 0, stream>>>(T, offs, N);
    gemm_mfma<<<dim3((N + 63) / 64, 4), 256, 0, stream>>>(x, wth, wtl, b, Aarr, Barr, N);
    scatter2_k<<<NBLK_H, 256, 0, stream>>>(src, dst, T, ssrc, E, N, chunk);
    node_max<<<N, 256, 0, stream>>>(Aarr, Barr, offs, ssrc, out, N);
}